// Round 1
// baseline (1068.959 us; speedup 1.0000x reference)
//
#include <hip/hip_runtime.h>
#include <cstdint>

// Problem constants (reference: B=16, DIM=128, H=W=64)
#define NPOS 4096          // H*W
#define CHT  768           // workspace channel count per batch (qkv_ca size)
#define NB   16

// ---------------------------------------------------------------------------
// Generic batched GEMM:  C[b] (O x 4096) = A (O x K) @ B[b] (K x 4096) [+ R[b]]
// A = weights (row-major, shared across batch). 64x64 output tile, BK=32.
// ---------------------------------------------------------------------------
__global__ __launch_bounds__(256)
void gemm_k(const float* __restrict__ A, const float* __restrict__ B,
            const float* __restrict__ R, float* __restrict__ C,
            int K, int64_t sB, int64_t sR, int64_t sC)
{
    const int tid = threadIdx.x;
    const int b   = blockIdx.z;
    const int n0  = blockIdx.x * 64;
    const int o0  = blockIdx.y * 64;
    const float* Bb = B + (int64_t)b * sB;

    __shared__ float As[32][66];   // [k][m], pad 66 -> conflict-free transpose store
    __shared__ float Bs[32][64];   // [k][n], float4-aligned

    const int tm = tid >> 4;        // 0..15  (m micro-tile)
    const int tn = tid & 15;        // 0..15  (n micro-tile)
    float acc[4][4] = {};

    const int ar = tid >> 3;        // 0..31 A row
    const int ak = (tid & 7) << 2;  // A k-col (float4)
    const int br = tid >> 4;        // 0..15 B row
    const int bn = (tid & 15) << 2; // B n-col (float4)

    for (int k0 = 0; k0 < K; k0 += 32) {
        #pragma unroll
        for (int p = 0; p < 2; p++) {
            int r = ar + p * 32;
            float4 a4 = *(const float4*)&A[(int64_t)(o0 + r) * K + k0 + ak];
            As[ak + 0][r] = a4.x; As[ak + 1][r] = a4.y;
            As[ak + 2][r] = a4.z; As[ak + 3][r] = a4.w;
        }
        #pragma unroll
        for (int p = 0; p < 2; p++) {
            int r = br + p * 16;
            *(float4*)&Bs[r][bn] = *(const float4*)&Bb[(int64_t)(k0 + r) * NPOS + n0 + bn];
        }
        __syncthreads();
        #pragma unroll 8
        for (int kk = 0; kk < 32; kk++) {
            float a0 = As[kk][tm*4+0], a1 = As[kk][tm*4+1];
            float a2 = As[kk][tm*4+2], a3 = As[kk][tm*4+3];
            float4 b4 = *(const float4*)&Bs[kk][tn*4];
            acc[0][0] += a0*b4.x; acc[0][1] += a0*b4.y; acc[0][2] += a0*b4.z; acc[0][3] += a0*b4.w;
            acc[1][0] += a1*b4.x; acc[1][1] += a1*b4.y; acc[1][2] += a1*b4.z; acc[1][3] += a1*b4.w;
            acc[2][0] += a2*b4.x; acc[2][1] += a2*b4.y; acc[2][2] += a2*b4.z; acc[2][3] += a2*b4.w;
            acc[3][0] += a3*b4.x; acc[3][1] += a3*b4.y; acc[3][2] += a3*b4.z; acc[3][3] += a3*b4.w;
        }
        __syncthreads();
    }

    float* Cb = C + (int64_t)b * sC;
    #pragma unroll
    for (int i = 0; i < 4; i++) {
        int o = o0 + tm * 4 + i;
        float4 v = make_float4(acc[i][0], acc[i][1], acc[i][2], acc[i][3]);
        if (R) {
            const float* Rb = R + (int64_t)b * sR;
            float4 r4 = *(const float4*)&Rb[(int64_t)o * NPOS + n0 + tn*4];
            v.x += r4.x; v.y += r4.y; v.z += r4.z; v.w += r4.w;
        }
        *(float4*)&Cb[(int64_t)o * NPOS + n0 + tn*4] = v;
    }
}

// ---------------------------------------------------------------------------
// Channel-attention stats: per (b,h) compute S = Q K^T (32x32 over n=4096),
// row norms of Q,K, then attn = softmax(S * temp / (|q||k|)).
// Q,K unnormalized; dividing S by norms == normalizing first (exact algebra).
// One block per (b,h): 128 blocks.
// ---------------------------------------------------------------------------
__global__ __launch_bounds__(256)
void ca_attn_k(const float* __restrict__ qkv, const float* __restrict__ temp,
               float* __restrict__ attn)
{
    const int bh = blockIdx.x;
    const int b = bh >> 3, h = bh & 7;
    const float* Q  = qkv + ((int64_t)b * CHT + h * 32) * NPOS;
    const float* Kp = qkv + ((int64_t)b * CHT + 256 + h * 32) * NPOS;

    __shared__ float Qs[32][66], Ks[32][66];
    __shared__ float Ss[32][33];
    __shared__ float nqs[32], nks[32];

    const int tid = threadIdx.x;
    const int c  = tid & 31;
    const int dq = tid >> 5;           // 0..7 -> d-range dq*4..dq*4+3
    float s[4] = {0.f, 0.f, 0.f, 0.f};
    float sq = 0.f, sk = 0.f;

    const int lr = tid >> 4;           // 0..15
    const int lc = (tid & 15) << 2;    // 0..60

    for (int nc0 = 0; nc0 < NPOS; nc0 += 64) {
        #pragma unroll
        for (int p = 0; p < 2; p++) {
            int r = lr + p * 16;
            float4 q4 = *(const float4*)&Q [(int64_t)r * NPOS + nc0 + lc];
            float4 k4 = *(const float4*)&Kp[(int64_t)r * NPOS + nc0 + lc];
            Qs[r][lc+0] = q4.x; Qs[r][lc+1] = q4.y; Qs[r][lc+2] = q4.z; Qs[r][lc+3] = q4.w;
            Ks[r][lc+0] = k4.x; Ks[r][lc+1] = k4.y; Ks[r][lc+2] = k4.z; Ks[r][lc+3] = k4.w;
        }
        __syncthreads();
        #pragma unroll 8
        for (int kk = 0; kk < 64; kk++) {
            float q = Qs[c][kk];
            s[0] += q * Ks[dq*4+0][kk];
            s[1] += q * Ks[dq*4+1][kk];
            s[2] += q * Ks[dq*4+2][kk];
            s[3] += q * Ks[dq*4+3][kk];
        }
        if (tid < 32) {
            #pragma unroll 8
            for (int kk = 0; kk < 64; kk++) {
                float q = Qs[tid][kk]; sq += q * q;
                float k = Ks[tid][kk]; sk += k * k;
            }
        }
        __syncthreads();
    }

    Ss[c][dq*4+0] = s[0]; Ss[c][dq*4+1] = s[1];
    Ss[c][dq*4+2] = s[2]; Ss[c][dq*4+3] = s[3];
    if (tid < 32) {
        nqs[tid] = fmaxf(sqrtf(sq), 1e-12f);
        nks[tid] = fmaxf(sqrtf(sk), 1e-12f);
    }
    __syncthreads();

    if (tid < 32) {
        const int cc = tid;
        float tn_ = temp[h] / nqs[cc];
        float vals[32];
        float mx = -1e30f;
        #pragma unroll
        for (int d = 0; d < 32; d++) {
            float v = Ss[cc][d] * tn_ / nks[d];
            vals[d] = v;
            mx = fmaxf(mx, v);
        }
        float sum = 0.f;
        #pragma unroll
        for (int d = 0; d < 32; d++) { vals[d] = __expf(vals[d] - mx); sum += vals[d]; }
        float inv = 1.f / sum;
        float* ap = attn + ((int64_t)bh * 32 + cc) * 32;
        #pragma unroll
        for (int d = 0; d < 32; d++) ap[d] = vals[d] * inv;
    }
}

// ---------------------------------------------------------------------------
// Channel-attention out = attn(32x32) @ V(32x4096), written into the Q slot.
// grid (16 n-tiles of 256, 128 bh)
// ---------------------------------------------------------------------------
__global__ __launch_bounds__(256)
void ca_av_k(const float* __restrict__ qkv, const float* __restrict__ attn,
             float* __restrict__ outp)
{
    const int bh = blockIdx.y, b = bh >> 3, h = bh & 7;
    const float* V = qkv + ((int64_t)b * CHT + 512 + h * 32) * NPOS;
    float* O = outp + ((int64_t)b * CHT + h * 32) * NPOS;

    __shared__ float As[1024];
    ((float4*)As)[threadIdx.x] = ((const float4*)(attn + (int64_t)bh * 1024))[threadIdx.x & 255];
    __syncthreads();

    const int n = blockIdx.x * 256 + threadIdx.x;
    float acc[32];
    #pragma unroll
    for (int c = 0; c < 32; c++) acc[c] = 0.f;

    #pragma unroll 2
    for (int d0 = 0; d0 < 32; d0 += 4) {
        float v0 = V[(int64_t)(d0+0) * NPOS + n];
        float v1 = V[(int64_t)(d0+1) * NPOS + n];
        float v2 = V[(int64_t)(d0+2) * NPOS + n];
        float v3 = V[(int64_t)(d0+3) * NPOS + n];
        #pragma unroll
        for (int c = 0; c < 32; c++) {
            float4 a = *(const float4*)&As[c * 32 + d0];
            acc[c] += a.x * v0 + a.y * v1 + a.z * v2 + a.w * v3;
        }
    }
    #pragma unroll
    for (int c = 0; c < 32; c++) O[(int64_t)c * NPOS + n] = acc[c];
}

// ---------------------------------------------------------------------------
// CSWin window attention. One block per (window, batch, head); 256 threads =
// 256 tokens. K,V staged in LDS [8][260] (rows 16B-aligned, broadcast reads).
// Two-pass softmax (recompute dot), O = softmax(QK^T)*V + lepe.
// HORIZ: window = 64 rows x 4 cols (p1=64,p2=4); else 4 rows x 64 cols.
// ---------------------------------------------------------------------------
template<int HORIZ>
__global__ __launch_bounds__(256)
void cswin_k(float* __restrict__ base, int64_t qOff, int64_t kOff, int64_t vOff,
             int64_t lOff, int64_t oOff)
{
    const float SCALE = 0.25f;   // (DIM/NH_CS)^-0.5 = 16^-0.5
    const int wnd = blockIdx.x, b = blockIdx.y, h = blockIdx.z;
    const int64_t bb = (int64_t)b * (CHT * NPOS) + (int64_t)h * 8 * NPOS;
    const float* Qp = base + bb + qOff;
    const float* Kp = base + bb + kOff;
    const float* Vp = base + bb + vOff;
    const float* Lp = base + bb + lOff;
    float*       Op = base + bb + oOff;

    const int t = threadIdx.x;
    int pos;
    if (HORIZ) pos = (t >> 2) * 64 + wnd * 4 + (t & 3);
    else       pos = (wnd * 4 + (t >> 6)) * 64 + (t & 63);

    __shared__ float Ks[8][260], Vs[8][260];
    float q[8];
    #pragma unroll
    for (int ch = 0; ch < 8; ch++) {
        Ks[ch][t] = Kp[(int64_t)ch * NPOS + pos];
        Vs[ch][t] = Vp[(int64_t)ch * NPOS + pos];
        q[ch] = Qp[(int64_t)ch * NPOS + pos] * SCALE;
    }
    __syncthreads();

    // pass 1: row max
    float mx = -1e30f;
    for (int k = 0; k < 256; k += 4) {
        float s0 = 0.f, s1 = 0.f, s2 = 0.f, s3 = 0.f;
        #pragma unroll
        for (int ch = 0; ch < 8; ch++) {
            float4 kv = *(const float4*)&Ks[ch][k];
            s0 += q[ch] * kv.x; s1 += q[ch] * kv.y;
            s2 += q[ch] * kv.z; s3 += q[ch] * kv.w;
        }
        mx = fmaxf(mx, fmaxf(fmaxf(s0, s1), fmaxf(s2, s3)));
    }
    // pass 2: exp, sum, P@V
    float l = 0.f;
    float acc[8];
    #pragma unroll
    for (int ch = 0; ch < 8; ch++) acc[ch] = 0.f;
    for (int k = 0; k < 256; k += 4) {
        float s0 = 0.f, s1 = 0.f, s2 = 0.f, s3 = 0.f;
        #pragma unroll
        for (int ch = 0; ch < 8; ch++) {
            float4 kv = *(const float4*)&Ks[ch][k];
            s0 += q[ch] * kv.x; s1 += q[ch] * kv.y;
            s2 += q[ch] * kv.z; s3 += q[ch] * kv.w;
        }
        float p0 = __expf(s0 - mx), p1 = __expf(s1 - mx);
        float p2 = __expf(s2 - mx), p3 = __expf(s3 - mx);
        l += (p0 + p1) + (p2 + p3);
        #pragma unroll
        for (int ch = 0; ch < 8; ch++) {
            float4 vv = *(const float4*)&Vs[ch][k];
            acc[ch] += p0 * vv.x + p1 * vv.y + p2 * vv.z + p3 * vv.w;
        }
    }
    float inv = 1.f / l;
    #pragma unroll
    for (int ch = 0; ch < 8; ch++)
        Op[(int64_t)ch * NPOS + pos] = acc[ch] * inv + Lp[(int64_t)ch * NPOS + pos];
}

// ---------------------------------------------------------------------------
// Launch: full pipeline.
// ws layout (floats): buf[16*768*4096] | x1[16*128*4096] | attn[16*8*32*32]
//   buf phase 1 (CA):  Q(0..255) K(256..511) V(512..767); out_ca overwrites Q.
//   buf phase 2 (CS):  q_all(0..127) k_all(128..255) v_all(256..383)
//                      vv_lepe(384..447) out_h(448..511) out_v(512..575)
// ---------------------------------------------------------------------------
extern "C" void kernel_launch(void* const* d_in, const int* in_sizes, int n_in,
                              void* d_out, int out_size, void* d_ws, size_t ws_size,
                              hipStream_t stream)
{
    (void)in_sizes; (void)n_in; (void)out_size; (void)ws_size;
    const float* x         = (const float*)d_in[0];
    const float* ca_temp   = (const float*)d_in[1];
    const float* ca_qkv_w  = (const float*)d_in[2];
    const float* ca_proj_w = (const float*)d_in[3];
    const float* cs_qk_w   = (const float*)d_in[4];
    const float* cs_v_w    = (const float*)d_in[5];
    const float* cs_vv_w   = (const float*)d_in[6];
    /* d_in[7] = cs_vh_w is unused by the reference */
    const float* cs_proj_w = (const float*)d_in[8];
    float* out = (float*)d_out;

    float* buf  = (float*)d_ws;
    float* x1   = buf + (int64_t)NB * CHT * NPOS;
    float* attn = x1 + (int64_t)NB * 128 * NPOS;

    const int64_t SB = (int64_t)CHT * NPOS;   // workspace batch stride
    const int64_t SX = (int64_t)128 * NPOS;   // x / x1 / out batch stride
    dim3 blk(256);

    // 1. qkv_ca = Wqkv(768x128) @ x
    gemm_k<<<dim3(64, 12, NB), blk, 0, stream>>>(ca_qkv_w, x, nullptr, buf, 128, SX, 0, SB);
    // 2. CA attention matrix (with norms + softmax)
    ca_attn_k<<<dim3(128), blk, 0, stream>>>(buf, ca_temp, attn);
    // 3. out_ca = attn @ V  (into Q slot)
    ca_av_k<<<dim3(16, 128), blk, 0, stream>>>(buf, attn, buf);
    // 4. x1 = x + Wproj(128x256) @ out_ca
    gemm_k<<<dim3(64, 2, NB), blk, 0, stream>>>(ca_proj_w, buf, x, x1, 256, SB, SX, SX);
    // 5. CSWin projections
    gemm_k<<<dim3(64, 4, NB), blk, 0, stream>>>(cs_qk_w, x1, nullptr, buf, 128, SX, 0, SB);
    gemm_k<<<dim3(64, 2, NB), blk, 0, stream>>>(cs_v_w,  x1, nullptr, buf + (int64_t)256 * NPOS, 128, SX, 0, SB);
    gemm_k<<<dim3(64, 1, NB), blk, 0, stream>>>(cs_vv_w, buf + (int64_t)320 * NPOS, nullptr,
                                                buf + (int64_t)384 * NPOS, 64, SB, 0, SB);
    // 6. window attention: horizontal (q_h,k_h,v_h, lepe=v_h) and vertical
    cswin_k<1><<<dim3(16, NB, 8), blk, 0, stream>>>(buf, (int64_t)0,          (int64_t)128 * NPOS,
                                                    (int64_t)256 * NPOS, (int64_t)256 * NPOS,
                                                    (int64_t)448 * NPOS);
    cswin_k<0><<<dim3(16, NB, 8), blk, 0, stream>>>(buf, (int64_t)64 * NPOS,  (int64_t)192 * NPOS,
                                                    (int64_t)320 * NPOS, (int64_t)384 * NPOS,
                                                    (int64_t)512 * NPOS);
    // 7. out = x1 + Wproj_cs(128x128) @ concat(out_h, out_v)
    gemm_k<<<dim3(64, 2, NB), blk, 0, stream>>>(cs_proj_w, buf + (int64_t)448 * NPOS, x1, out,
                                                128, SB, SX, SX);
}

// Round 2
// 815.573 us; speedup vs baseline: 1.3107x; 1.3107x over previous
//
#include <hip/hip_runtime.h>
#include <cstdint>

// Problem constants (reference: B=16, DIM=128, H=W=64)
#define NPOS 4096          // H*W
#define CHT  768           // workspace channel count per batch (qkv_ca size)
#define NB   16

// ---------------------------------------------------------------------------
// Generic batched GEMM:  C[b] (O x 4096) = A (O x K) @ B[b] (K x 4096) [+ R[b]]
// A = weights (row-major, shared across batch). 64x64 output tile, BK=32.
// ---------------------------------------------------------------------------
__global__ __launch_bounds__(256)
void gemm_k(const float* __restrict__ A, const float* __restrict__ B,
            const float* __restrict__ R, float* __restrict__ C,
            int K, int64_t sB, int64_t sR, int64_t sC)
{
    const int tid = threadIdx.x;
    const int b   = blockIdx.z;
    const int n0  = blockIdx.x * 64;
    const int o0  = blockIdx.y * 64;
    const float* Bb = B + (int64_t)b * sB;

    __shared__ float As[32][68];   // [k][m], pad 68 -> 16B-aligned rows (float4 reads)
    __shared__ float Bs[32][64];   // [k][n], float4-aligned

    const int tm = tid >> 4;        // 0..15  (m micro-tile)
    const int tn = tid & 15;        // 0..15  (n micro-tile)
    float acc[4][4] = {};

    const int ar = tid >> 3;        // 0..31 A row
    const int ak = (tid & 7) << 2;  // A k-col (float4)
    const int br = tid >> 4;        // 0..15 B row
    const int bn = (tid & 15) << 2; // B n-col (float4)

    for (int k0 = 0; k0 < K; k0 += 32) {
        #pragma unroll
        for (int p = 0; p < 2; p++) {
            int r = ar + p * 32;
            float4 a4 = *(const float4*)&A[(int64_t)(o0 + r) * K + k0 + ak];
            As[ak + 0][r] = a4.x; As[ak + 1][r] = a4.y;
            As[ak + 2][r] = a4.z; As[ak + 3][r] = a4.w;
        }
        #pragma unroll
        for (int p = 0; p < 2; p++) {
            int r = br + p * 16;
            *(float4*)&Bs[r][bn] = *(const float4*)&Bb[(int64_t)(k0 + r) * NPOS + n0 + bn];
        }
        __syncthreads();
        #pragma unroll 8
        for (int kk = 0; kk < 32; kk++) {
            float4 a4 = *(const float4*)&As[kk][tm*4];
            float4 b4 = *(const float4*)&Bs[kk][tn*4];
            acc[0][0] += a4.x*b4.x; acc[0][1] += a4.x*b4.y; acc[0][2] += a4.x*b4.z; acc[0][3] += a4.x*b4.w;
            acc[1][0] += a4.y*b4.x; acc[1][1] += a4.y*b4.y; acc[1][2] += a4.y*b4.z; acc[1][3] += a4.y*b4.w;
            acc[2][0] += a4.z*b4.x; acc[2][1] += a4.z*b4.y; acc[2][2] += a4.z*b4.z; acc[2][3] += a4.z*b4.w;
            acc[3][0] += a4.w*b4.x; acc[3][1] += a4.w*b4.y; acc[3][2] += a4.w*b4.z; acc[3][3] += a4.w*b4.w;
        }
        __syncthreads();
    }

    float* Cb = C + (int64_t)b * sC;
    #pragma unroll
    for (int i = 0; i < 4; i++) {
        int o = o0 + tm * 4 + i;
        float4 v = make_float4(acc[i][0], acc[i][1], acc[i][2], acc[i][3]);
        if (R) {
            const float* Rb = R + (int64_t)b * sR;
            float4 r4 = *(const float4*)&Rb[(int64_t)o * NPOS + n0 + tn*4];
            v.x += r4.x; v.y += r4.y; v.z += r4.z; v.w += r4.w;
        }
        *(float4*)&Cb[(int64_t)o * NPOS + n0 + tn*4] = v;
    }
}

// ---------------------------------------------------------------------------
// CA phase A: partial S = Q K^T and partial row norms over an n-chunk of 512.
// grid (8 chunks, 128 bh), 256 threads.
// part layout: [bh][chunk][1088] = 1024 S (idx d*32+c) + 32 sq + 32 sk
// ---------------------------------------------------------------------------
__global__ __launch_bounds__(256)
void ca_partial_k(const float* __restrict__ qkv, float* __restrict__ part)
{
    const int chunk = blockIdx.x;
    const int bh = blockIdx.y;
    const int b = bh >> 3, h = bh & 7;
    const float* Q  = qkv + ((int64_t)b * CHT + h * 32) * NPOS;
    const float* Kp = qkv + ((int64_t)b * CHT + 256 + h * 32) * NPOS;

    __shared__ float Qs[32][68], Ks[32][68];
    __shared__ float nrm[2][32][8];

    const int tid = threadIdx.x;
    const int c  = tid & 31;       // S row / norm row
    const int dq = tid >> 5;       // 0..7: S col group (dq*4..+3) and norm k-seg
    float s[4] = {0.f, 0.f, 0.f, 0.f};
    float sqp = 0.f, skp = 0.f;

    const int lr = tid >> 4;           // 0..15
    const int lc = (tid & 15) << 2;    // 0..60

    const int nbase = chunk * 512;
    for (int nc0 = nbase; nc0 < nbase + 512; nc0 += 64) {
        #pragma unroll
        for (int p = 0; p < 2; p++) {
            int r = lr + p * 16;
            *(float4*)&Qs[r][lc] = *(const float4*)&Q [(int64_t)r * NPOS + nc0 + lc];
            *(float4*)&Ks[r][lc] = *(const float4*)&Kp[(int64_t)r * NPOS + nc0 + lc];
        }
        __syncthreads();
        #pragma unroll
        for (int kk = 0; kk < 64; kk += 4) {
            float4 qv = *(const float4*)&Qs[c][kk];
            #pragma unroll
            for (int j = 0; j < 4; j++) {
                float4 kv = *(const float4*)&Ks[dq*4+j][kk];
                s[j] += qv.x*kv.x + qv.y*kv.y + qv.z*kv.z + qv.w*kv.w;
            }
        }
        // norm partial: row c, cols [dq*8, dq*8+8)
        #pragma unroll
        for (int kk = dq*8; kk < dq*8+8; kk += 4) {
            float4 qv = *(const float4*)&Qs[c][kk];
            float4 kv = *(const float4*)&Ks[c][kk];
            sqp += qv.x*qv.x + qv.y*qv.y + qv.z*qv.z + qv.w*qv.w;
            skp += kv.x*kv.x + kv.y*kv.y + kv.z*kv.z + kv.w*kv.w;
        }
        __syncthreads();
    }

    float* pp = part + ((int64_t)bh * 8 + chunk) * 1088;
    #pragma unroll
    for (int j = 0; j < 4; j++)
        pp[(dq*4+j)*32 + c] = s[j];

    nrm[0][c][dq] = sqp;
    nrm[1][c][dq] = skp;
    __syncthreads();
    if (tid < 64) {
        int row = tid & 31, which = tid >> 5;
        float acc = 0.f;
        #pragma unroll
        for (int p = 0; p < 8; p++) acc += nrm[which][row][p];
        pp[1024 + which*32 + row] = acc;
    }
}

// ---------------------------------------------------------------------------
// CA phase B: reduce partials, apply norms + temp, softmax -> attn[bh][32][32]
// grid 128, 256 threads
// ---------------------------------------------------------------------------
__global__ __launch_bounds__(256)
void ca_reduce_k(const float* __restrict__ part, const float* __restrict__ temp,
                 float* __restrict__ attn)
{
    const int bh = blockIdx.x;
    const int h = bh & 7;
    const float* pp = part + (int64_t)bh * 8 * 1088;

    __shared__ float Ss[1024];    // idx d*32+c
    __shared__ float nq[32], nk[32];

    const int tid = threadIdx.x;
    {
        float4 acc = make_float4(0.f, 0.f, 0.f, 0.f);
        #pragma unroll
        for (int p = 0; p < 8; p++) {
            float4 v = *(const float4*)&pp[p*1088 + tid*4];
            acc.x += v.x; acc.y += v.y; acc.z += v.z; acc.w += v.w;
        }
        *(float4*)&Ss[tid*4] = acc;
    }
    if (tid < 64) {
        int row = tid & 31, which = tid >> 5;
        float a = 0.f;
        #pragma unroll
        for (int p = 0; p < 8; p++) a += pp[p*1088 + 1024 + which*32 + row];
        float n = fmaxf(sqrtf(a), 1e-12f);
        if (which == 0) nq[row] = n; else nk[row] = n;
    }
    __syncthreads();

    if (tid < 32) {
        const int cc = tid;
        float tn_ = temp[h] / nq[cc];
        float vals[32];
        float mx = -1e30f;
        #pragma unroll
        for (int d = 0; d < 32; d++) {
            float v = Ss[d*32 + cc] * tn_ / nk[d];
            vals[d] = v;
            mx = fmaxf(mx, v);
        }
        float sum = 0.f;
        #pragma unroll
        for (int d = 0; d < 32; d++) { vals[d] = __expf(vals[d] - mx); sum += vals[d]; }
        float inv = 1.f / sum;
        float* ap = attn + ((int64_t)bh * 32 + cc) * 32;
        #pragma unroll
        for (int d = 0; d < 32; d++) ap[d] = vals[d] * inv;
    }
}

// ---------------------------------------------------------------------------
// Channel-attention out = attn(32x32) @ V(32x4096), written into the Q slot.
// grid (16 n-tiles of 256, 128 bh)
// ---------------------------------------------------------------------------
__global__ __launch_bounds__(256)
void ca_av_k(const float* __restrict__ qkv, const float* __restrict__ attn,
             float* __restrict__ outp)
{
    const int bh = blockIdx.y, b = bh >> 3, h = bh & 7;
    const float* V = qkv + ((int64_t)b * CHT + 512 + h * 32) * NPOS;
    float* O = outp + ((int64_t)b * CHT + h * 32) * NPOS;

    __shared__ float As[1024];
    ((float4*)As)[threadIdx.x] = ((const float4*)(attn + (int64_t)bh * 1024))[threadIdx.x & 255];
    __syncthreads();

    const int n = blockIdx.x * 256 + threadIdx.x;
    float acc[32];
    #pragma unroll
    for (int c = 0; c < 32; c++) acc[c] = 0.f;

    #pragma unroll 2
    for (int d0 = 0; d0 < 32; d0 += 4) {
        float v0 = V[(int64_t)(d0+0) * NPOS + n];
        float v1 = V[(int64_t)(d0+1) * NPOS + n];
        float v2 = V[(int64_t)(d0+2) * NPOS + n];
        float v3 = V[(int64_t)(d0+3) * NPOS + n];
        #pragma unroll
        for (int c = 0; c < 32; c++) {
            float4 a = *(const float4*)&As[c * 32 + d0];
            acc[c] += a.x * v0 + a.y * v1 + a.z * v2 + a.w * v3;
        }
    }
    #pragma unroll
    for (int c = 0; c < 32; c++) O[(int64_t)c * NPOS + n] = acc[c];
}

// ---------------------------------------------------------------------------
// CSWin window attention, single pass. One block per (window,b,h); 256 thr =
// 256 tokens. Softmax uses Cauchy-Schwarz bound B = |q|*max|k| >= row max;
// exp(s-B) cancels exactly in numerator/denominator (same softmax).
// ---------------------------------------------------------------------------
template<int HORIZ>
__global__ __launch_bounds__(256)
void cswin_k(float* __restrict__ base, int64_t qOff, int64_t kOff, int64_t vOff,
             int64_t lOff, int64_t oOff)
{
    const float SCALE = 0.25f;   // (DIM/NH_CS)^-0.5
    const int wnd = blockIdx.x, b = blockIdx.y, h = blockIdx.z;
    const int64_t bb = (int64_t)b * (CHT * NPOS) + (int64_t)h * 8 * NPOS;
    const float* Qp = base + bb + qOff;
    const float* Kp = base + bb + kOff;
    const float* Vp = base + bb + vOff;
    const float* Lp = base + bb + lOff;
    float*       Op = base + bb + oOff;

    const int t = threadIdx.x;
    int pos;
    if (HORIZ) pos = (t >> 2) * 64 + wnd * 4 + (t & 3);
    else       pos = (wnd * 4 + (t >> 6)) * 64 + (t & 63);

    __shared__ float Ks[8][260], Vs[8][260];
    __shared__ float wmax[4];
    float q[8];
    float qn = 0.f, kn = 0.f;
    #pragma unroll
    for (int ch = 0; ch < 8; ch++) {
        float kv = Kp[(int64_t)ch * NPOS + pos];
        Ks[ch][t] = kv; kn += kv * kv;
        Vs[ch][t] = Vp[(int64_t)ch * NPOS + pos];
        float qv = Qp[(int64_t)ch * NPOS + pos] * SCALE;
        q[ch] = qv; qn += qv * qv;
    }
    // block max of |k| (wave butterfly + 4-slot LDS)
    float knr = sqrtf(kn);
    #pragma unroll
    for (int o = 32; o > 0; o >>= 1) knr = fmaxf(knr, __shfl_xor(knr, o));
    if ((t & 63) == 0) wmax[t >> 6] = knr;
    __syncthreads();
    const float kmax = fmaxf(fmaxf(wmax[0], wmax[1]), fmaxf(wmax[2], wmax[3]));
    const float B = sqrtf(qn) * kmax;   // >= max_k (q . k_scaled)

    float l = 0.f;
    float acc[8];
    #pragma unroll
    for (int ch = 0; ch < 8; ch++) acc[ch] = 0.f;

    for (int k = 0; k < 256; k += 4) {
        float s0 = 0.f, s1 = 0.f, s2 = 0.f, s3 = 0.f;
        #pragma unroll
        for (int ch = 0; ch < 8; ch++) {
            float4 kv = *(const float4*)&Ks[ch][k];
            s0 += q[ch] * kv.x; s1 += q[ch] * kv.y;
            s2 += q[ch] * kv.z; s3 += q[ch] * kv.w;
        }
        float p0 = __expf(s0 - B), p1 = __expf(s1 - B);
        float p2 = __expf(s2 - B), p3 = __expf(s3 - B);
        l += (p0 + p1) + (p2 + p3);
        #pragma unroll
        for (int ch = 0; ch < 8; ch++) {
            float4 vv = *(const float4*)&Vs[ch][k];
            acc[ch] += p0 * vv.x + p1 * vv.y + p2 * vv.z + p3 * vv.w;
        }
    }
    float inv = 1.f / l;
    #pragma unroll
    for (int ch = 0; ch < 8; ch++)
        Op[(int64_t)ch * NPOS + pos] = acc[ch] * inv + Lp[(int64_t)ch * NPOS + pos];
}

// ---------------------------------------------------------------------------
// ws layout (floats): buf[16*768*4096] | x1[16*128*4096] | attn[16*8*32*32]
//   CA partials temporarily live in the x1 region (written later by step 4).
// ---------------------------------------------------------------------------
extern "C" void kernel_launch(void* const* d_in, const int* in_sizes, int n_in,
                              void* d_out, int out_size, void* d_ws, size_t ws_size,
                              hipStream_t stream)
{
    (void)in_sizes; (void)n_in; (void)out_size; (void)ws_size;
    const float* x         = (const float*)d_in[0];
    const float* ca_temp   = (const float*)d_in[1];
    const float* ca_qkv_w  = (const float*)d_in[2];
    const float* ca_proj_w = (const float*)d_in[3];
    const float* cs_qk_w   = (const float*)d_in[4];
    const float* cs_v_w    = (const float*)d_in[5];
    const float* cs_vv_w   = (const float*)d_in[6];
    /* d_in[7] = cs_vh_w unused by the reference */
    const float* cs_proj_w = (const float*)d_in[8];
    float* out = (float*)d_out;

    float* buf  = (float*)d_ws;
    float* x1   = buf + (int64_t)NB * CHT * NPOS;
    float* attn = x1 + (int64_t)NB * 128 * NPOS;
    float* part = x1;   // 128*8*1088 floats, overwritten later by real x1

    const int64_t SB = (int64_t)CHT * NPOS;
    const int64_t SX = (int64_t)128 * NPOS;
    dim3 blk(256);

    // 1. qkv_ca = Wqkv(768x128) @ x
    gemm_k<<<dim3(64, 12, NB), blk, 0, stream>>>(ca_qkv_w, x, nullptr, buf, 128, SX, 0, SB);
    // 2. CA attention: split-N partials, then reduce+softmax
    ca_partial_k<<<dim3(8, 128), blk, 0, stream>>>(buf, part);
    ca_reduce_k<<<dim3(128), blk, 0, stream>>>(part, ca_temp, attn);
    // 3. out_ca = attn @ V  (into Q slot)
    ca_av_k<<<dim3(16, 128), blk, 0, stream>>>(buf, attn, buf);
    // 4. x1 = x + Wproj(128x256) @ out_ca
    gemm_k<<<dim3(64, 2, NB), blk, 0, stream>>>(ca_proj_w, buf, x, x1, 256, SB, SX, SX);
    // 5. CSWin projections
    gemm_k<<<dim3(64, 4, NB), blk, 0, stream>>>(cs_qk_w, x1, nullptr, buf, 128, SX, 0, SB);
    gemm_k<<<dim3(64, 2, NB), blk, 0, stream>>>(cs_v_w,  x1, nullptr, buf + (int64_t)256 * NPOS, 128, SX, 0, SB);
    gemm_k<<<dim3(64, 1, NB), blk, 0, stream>>>(cs_vv_w, buf + (int64_t)320 * NPOS, nullptr,
                                                buf + (int64_t)384 * NPOS, 64, SB, 0, SB);
    // 6. window attention: horizontal then vertical
    cswin_k<1><<<dim3(16, NB, 8), blk, 0, stream>>>(buf, (int64_t)0,          (int64_t)128 * NPOS,
                                                    (int64_t)256 * NPOS, (int64_t)256 * NPOS,
                                                    (int64_t)448 * NPOS);
    cswin_k<0><<<dim3(16, NB, 8), blk, 0, stream>>>(buf, (int64_t)64 * NPOS,  (int64_t)192 * NPOS,
                                                    (int64_t)320 * NPOS, (int64_t)384 * NPOS,
                                                    (int64_t)512 * NPOS);
    // 7. out = x1 + Wproj_cs(128x128) @ concat(out_h, out_v)
    gemm_k<<<dim3(64, 2, NB), blk, 0, stream>>>(cs_proj_w, buf + (int64_t)448 * NPOS, x1, out,
                                                128, SB, SX, SX);
}

// Round 15
// 668.931 us; speedup vs baseline: 1.5980x; 1.2192x over previous
//
#include <hip/hip_runtime.h>
#include <cstdint>

// Problem constants (reference: B=16, DIM=128, H=W=64)
#define NPOS 4096          // H*W
#define CHB  576           // cswin workspace channels per batch
#define NB   16

// ---------------------------------------------------------------------------
// gemm128: C[b](O x N) = A[b](O x K) @ B[b](K x N) [+ R[b]], tile 64(O)x128(N),
// BK=32, 256 threads, 8x4 micro-tile. O,K multiples of 64/32. N multiple of 128.
// ---------------------------------------------------------------------------
__global__ __launch_bounds__(256)
void gemm128(const float* __restrict__ A, const float* __restrict__ B,
             const float* __restrict__ R, float* __restrict__ C,
             int K, int64_t ldB, int64_t ldC,
             int64_t sA, int64_t sB, int64_t sR, int64_t sC)
{
    const int t  = threadIdx.x;
    const int b  = blockIdx.z;
    const int n0 = blockIdx.x * 128;
    const int o0 = blockIdx.y * 64;
    const float* Ab = A + (int64_t)b * sA;
    const float* Bb = B + (int64_t)b * sB;

    __shared__ float As[32][68];    // [k][o-row], swizzled store (conflict-free)
    __shared__ float Bs[32][132];   // [k][n]

    const int to = t & 7;           // 0..7  -> O rows to*8..+7
    const int tn = t >> 3;          // 0..31 -> N cols tn*4..+3
    float acc[8][4] = {};

    // A staging map: ar = t&31 (row), ak = (t>>5)*4 (k), 2 row-passes
    const int ar = t & 31;
    const int ak = (t >> 5) << 2;
    // B staging map: bn = (t&31)*4 (col), br = t>>5 (row), 4 row-passes
    const int bn = (t & 31) << 2;
    const int br = t >> 5;

    for (int k0 = 0; k0 < K; k0 += 32) {
        #pragma unroll
        for (int p = 0; p < 2; p++) {
            int r = ar + 32 * p;
            float4 a4 = *(const float4*)&Ab[(int64_t)(o0 + r) * K + k0 + ak];
            As[ak + 0][r] = a4.x; As[ak + 1][r] = a4.y;
            As[ak + 2][r] = a4.z; As[ak + 3][r] = a4.w;
        }
        #pragma unroll
        for (int p = 0; p < 4; p++) {
            int r = br + 8 * p;
            *(float4*)&Bs[r][bn] = *(const float4*)&Bb[(int64_t)(k0 + r) * ldB + n0 + bn];
        }
        __syncthreads();
        #pragma unroll 4
        for (int kk = 0; kk < 32; kk++) {
            float a[8];
            *(float4*)&a[0] = *(const float4*)&As[kk][to * 8];
            *(float4*)&a[4] = *(const float4*)&As[kk][to * 8 + 4];
            float4 b4 = *(const float4*)&Bs[kk][tn * 4];
            #pragma unroll
            for (int i = 0; i < 8; i++) {
                acc[i][0] += a[i] * b4.x; acc[i][1] += a[i] * b4.y;
                acc[i][2] += a[i] * b4.z; acc[i][3] += a[i] * b4.w;
            }
        }
        __syncthreads();
    }

    float* Cb = C + (int64_t)b * sC;
    const float* Rb = R ? (R + (int64_t)b * sR) : nullptr;
    #pragma unroll
    for (int i = 0; i < 8; i++) {
        int o = o0 + to * 8 + i;
        float4 v = make_float4(acc[i][0], acc[i][1], acc[i][2], acc[i][3]);
        if (Rb) {
            float4 r4 = *(const float4*)&Rb[(int64_t)o * ldC + n0 + tn * 4];
            v.x += r4.x; v.y += r4.y; v.z += r4.z; v.w += r4.w;
        }
        *(float4*)&Cb[(int64_t)o * ldC + n0 + tn * 4] = v;
    }
}

// ---------------------------------------------------------------------------
// Gram partials: P[b*32+chunk] (128x128) = X[:,chunk] X[:,chunk]^T over 128 pos.
// grid (32, 16), 256 threads, 8x8 micro (both operands from one LDS tile).
// ---------------------------------------------------------------------------
__global__ __launch_bounds__(256)
void gram_k(const float* __restrict__ x, float* __restrict__ P)
{
    const int chunk = blockIdx.x, b = blockIdx.y;
    const float* X = x + (int64_t)b * 128 * NPOS;

    __shared__ float Xs[32][132];   // [n'][c]
    const int t  = threadIdx.x;
    const int ti = t >> 4, tj = t & 15;
    float acc[8][8] = {};

    const int lc = t >> 3;          // channel 0..31 (+32p)
    const int ln = (t & 7) << 2;    // n' 0,4,...,28

    for (int k0 = 0; k0 < 128; k0 += 32) {
        const int nbase = chunk * 128 + k0;
        #pragma unroll
        for (int p = 0; p < 4; p++) {
            int c = lc + 32 * p;
            float4 v = *(const float4*)&X[(int64_t)c * NPOS + nbase + ln];
            Xs[ln + 0][c] = v.x; Xs[ln + 1][c] = v.y;
            Xs[ln + 2][c] = v.z; Xs[ln + 3][c] = v.w;
        }
        __syncthreads();
        #pragma unroll 2
        for (int kk = 0; kk < 32; kk++) {
            float a[8], c8[8];
            *(float4*)&a[0]  = *(const float4*)&Xs[kk][ti * 8];
            *(float4*)&a[4]  = *(const float4*)&Xs[kk][ti * 8 + 4];
            *(float4*)&c8[0] = *(const float4*)&Xs[kk][tj * 8];
            *(float4*)&c8[4] = *(const float4*)&Xs[kk][tj * 8 + 4];
            #pragma unroll
            for (int i = 0; i < 8; i++)
                #pragma unroll
                for (int j = 0; j < 8; j++)
                    acc[i][j] += a[i] * c8[j];
        }
        __syncthreads();
    }

    float* pp = P + (int64_t)(b * 32 + chunk) * 16384;
    #pragma unroll
    for (int i = 0; i < 8; i++) {
        *(float4*)&pp[(ti * 8 + i) * 128 + tj * 8]     = *(float4*)&acc[i][0];
        *(float4*)&pp[(ti * 8 + i) * 128 + tj * 8 + 4] = *(float4*)&acc[i][4];
    }
}

// G[b] = sum of 32 partials. grid (64, 16), 256 threads.
__global__ __launch_bounds__(256)
void gram_reduce_k(const float* __restrict__ P, float* __restrict__ G)
{
    const int b = blockIdx.y;
    const int e = blockIdx.x * 256 + threadIdx.x;
    float s = 0.f;
    #pragma unroll 8
    for (int c = 0; c < 32; c++) s += P[(int64_t)(b * 32 + c) * 16384 + e];
    G[(int64_t)b * 16384 + e] = s;
}

// ---------------------------------------------------------------------------
// Per (b,h): S = Wq G Wk^T, norms from diag quadratic forms, softmax(temp-scaled),
// N = A @ Wv  ->  AWv[b] rows h*32..+31. grid (8 h, 16 b), 256 threads.
// ---------------------------------------------------------------------------
__global__ __launch_bounds__(256)
void ca_small_k(const float* __restrict__ G, const float* __restrict__ qkv_w,
                const float* __restrict__ temp, float* __restrict__ AWv)
{
    const int h = blockIdx.x, b = blockIdx.y;
    const float* Gb = G + (int64_t)b * 16384;

    __shared__ float Wa[32][129];   // Wq
    __shared__ float Wb[32][129];   // Wk, then Wv
    __shared__ float Tmp[32][129];  // Tk = Wk G
    __shared__ float Ss[32][33];    // S, then A
    __shared__ float nqp[32][8], nkp[32][8];
    __shared__ float nk[32];

    const int t = threadIdx.x;
    const int r  = t & 31;
    const int cg = t >> 5;          // 0..7 col group of 16

    // stage Wq, Wk
    #pragma unroll
    for (int j = 0; j < 4; j++) {
        int col = cg * 16 + j * 4;
        *(float4*)&Wa[r][col] = *(const float4*)&qkv_w[(int64_t)(h * 32 + r) * 128 + col];
        *(float4*)&Wb[r][col] = *(const float4*)&qkv_w[(int64_t)(256 + h * 32 + r) * 128 + col];
    }
    __syncthreads();

    // pass 1: Tk = Wk G  (row r, cols cg*16..+15), kn partials
    {
        float acc[16];
        #pragma unroll
        for (int u = 0; u < 16; u++) acc[u] = 0.f;
        #pragma unroll 2
        for (int i = 0; i < 128; i++) {
            float w = Wb[r][i];
            const float* g = &Gb[i * 128 + cg * 16];
            float4 g0 = *(const float4*)&g[0],  g1 = *(const float4*)&g[4];
            float4 g2 = *(const float4*)&g[8],  g3 = *(const float4*)&g[12];
            acc[0] += w*g0.x; acc[1] += w*g0.y; acc[2] += w*g0.z; acc[3] += w*g0.w;
            acc[4] += w*g1.x; acc[5] += w*g1.y; acc[6] += w*g1.z; acc[7] += w*g1.w;
            acc[8] += w*g2.x; acc[9] += w*g2.y; acc[10]+= w*g2.z; acc[11]+= w*g2.w;
            acc[12]+= w*g3.x; acc[13]+= w*g3.y; acc[14]+= w*g3.z; acc[15]+= w*g3.w;
        }
        float np = 0.f;
        #pragma unroll
        for (int u = 0; u < 16; u++) {
            Tmp[r][cg * 16 + u] = acc[u];
            np += acc[u] * Wb[r][cg * 16 + u];
        }
        nkp[r][cg] = np;
    }
    __syncthreads();
    if (t < 32) {
        float s = 0.f;
        #pragma unroll
        for (int p = 0; p < 8; p++) s += nkp[t][p];
        nk[t] = fmaxf(sqrtf(s), 1e-12f);
    }
    // S[c][d] = sum_i Tk[d][i] * Wq[c][i]   (c = r, d = cg*4+j)
    {
        #pragma unroll
        for (int j = 0; j < 4; j++) {
            int d = cg * 4 + j;
            float s = 0.f;
            #pragma unroll 4
            for (int i = 0; i < 128; i++) s += Tmp[d][i] * Wa[r][i];
            Ss[r][d] = s;
        }
    }
    __syncthreads();

    // pass 2: Tq = Wq G (only diag quadratic form needed), stage Wv into Wb
    {
        float acc[16];
        #pragma unroll
        for (int u = 0; u < 16; u++) acc[u] = 0.f;
        #pragma unroll 2
        for (int i = 0; i < 128; i++) {
            float w = Wa[r][i];
            const float* g = &Gb[i * 128 + cg * 16];
            float4 g0 = *(const float4*)&g[0],  g1 = *(const float4*)&g[4];
            float4 g2 = *(const float4*)&g[8],  g3 = *(const float4*)&g[12];
            acc[0] += w*g0.x; acc[1] += w*g0.y; acc[2] += w*g0.z; acc[3] += w*g0.w;
            acc[4] += w*g1.x; acc[5] += w*g1.y; acc[6] += w*g1.z; acc[7] += w*g1.w;
            acc[8] += w*g2.x; acc[9] += w*g2.y; acc[10]+= w*g2.z; acc[11]+= w*g2.w;
            acc[12]+= w*g3.x; acc[13]+= w*g3.y; acc[14]+= w*g3.z; acc[15]+= w*g3.w;
        }
        float np = 0.f;
        #pragma unroll
        for (int u = 0; u < 16; u++) np += acc[u] * Wa[r][cg * 16 + u];
        nqp[r][cg] = np;
        #pragma unroll
        for (int j = 0; j < 4; j++) {
            int col = cg * 16 + j * 4;
            *(float4*)&Wb[r][col] = *(const float4*)&qkv_w[(int64_t)(512 + h * 32 + r) * 128 + col];
        }
    }
    __syncthreads();

    // softmax rows (threads 0..31), temp/norm scaling
    if (t < 32) {
        const int c = t;
        float s = 0.f;
        #pragma unroll
        for (int p = 0; p < 8; p++) s += nqp[c][p];
        float nqc = fmaxf(sqrtf(s), 1e-12f);
        float tn_ = temp[h] / nqc;
        float vals[32], mx = -1e30f;
        #pragma unroll
        for (int d = 0; d < 32; d++) {
            float v = Ss[c][d] * tn_ / nk[d];
            vals[d] = v; mx = fmaxf(mx, v);
        }
        float sum = 0.f;
        #pragma unroll
        for (int d = 0; d < 32; d++) { vals[d] = __expf(vals[d] - mx); sum += vals[d]; }
        float inv = 1.f / sum;
        #pragma unroll
        for (int d = 0; d < 32; d++) Ss[c][d] = vals[d] * inv;
    }
    __syncthreads();

    // N[r][col] = sum_d A[r][d] Wv[d][col] -> AWv global
    {
        float acc[16];
        #pragma unroll
        for (int u = 0; u < 16; u++) acc[u] = 0.f;
        #pragma unroll 4
        for (int d = 0; d < 32; d++) {
            float a = Ss[r][d];
            #pragma unroll
            for (int u = 0; u < 16; u++) acc[u] += a * Wb[d][cg * 16 + u];
        }
        float* op = AWv + (int64_t)b * 32768 + (int64_t)(h * 32 + r) * 128 + cg * 16;
        #pragma unroll
        for (int j = 0; j < 4; j++)
            *(float4*)&op[j * 4] = make_float4(acc[j*4], acc[j*4+1], acc[j*4+2], acc[j*4+3]);
    }
}

// ---------------------------------------------------------------------------
// CSWin window attention, single pass with Cauchy-Schwarz bound (exact softmax).
// ---------------------------------------------------------------------------
template<int HORIZ>
__global__ __launch_bounds__(256)
void cswin_k(float* __restrict__ base, int64_t qOff, int64_t kOff, int64_t vOff,
             int64_t lOff, int64_t oOff)
{
    const float SCALE = 0.25f;
    const int wnd = blockIdx.x, b = blockIdx.y, h = blockIdx.z;
    const int64_t bb = (int64_t)b * (CHB * NPOS) + (int64_t)h * 8 * NPOS;
    const float* Qp = base + bb + qOff;
    const float* Kp = base + bb + kOff;
    const float* Vp = base + bb + vOff;
    const float* Lp = base + bb + lOff;
    float*       Op = base + bb + oOff;

    const int t = threadIdx.x;
    int pos;
    if (HORIZ) pos = (t >> 2) * 64 + wnd * 4 + (t & 3);
    else       pos = (wnd * 4 + (t >> 6)) * 64 + (t & 63);

    __shared__ float Ks[8][260], Vs[8][260];
    __shared__ float wmax[4];
    float q[8];
    float qn = 0.f, kn = 0.f;
    #pragma unroll
    for (int ch = 0; ch < 8; ch++) {
        float kv = Kp[(int64_t)ch * NPOS + pos];
        Ks[ch][t] = kv; kn += kv * kv;
        Vs[ch][t] = Vp[(int64_t)ch * NPOS + pos];
        float qv = Qp[(int64_t)ch * NPOS + pos] * SCALE;
        q[ch] = qv; qn += qv * qv;
    }
    float knr = sqrtf(kn);
    #pragma unroll
    for (int o = 32; o > 0; o >>= 1) knr = fmaxf(knr, __shfl_xor(knr, o));
    if ((t & 63) == 0) wmax[t >> 6] = knr;
    __syncthreads();
    const float kmax = fmaxf(fmaxf(wmax[0], wmax[1]), fmaxf(wmax[2], wmax[3]));
    const float B = sqrtf(qn) * kmax;

    float l = 0.f;
    float acc[8];
    #pragma unroll
    for (int ch = 0; ch < 8; ch++) acc[ch] = 0.f;

    for (int k = 0; k < 256; k += 4) {
        float s0 = 0.f, s1 = 0.f, s2 = 0.f, s3 = 0.f;
        #pragma unroll
        for (int ch = 0; ch < 8; ch++) {
            float4 kv = *(const float4*)&Ks[ch][k];
            s0 += q[ch] * kv.x; s1 += q[ch] * kv.y;
            s2 += q[ch] * kv.z; s3 += q[ch] * kv.w;
        }
        float p0 = __expf(s0 - B), p1 = __expf(s1 - B);
        float p2 = __expf(s2 - B), p3 = __expf(s3 - B);
        l += (p0 + p1) + (p2 + p3);
        #pragma unroll
        for (int ch = 0; ch < 8; ch++) {
            float4 vv = *(const float4*)&Vs[ch][k];
            acc[ch] += p0 * vv.x + p1 * vv.y + p2 * vv.z + p3 * vv.w;
        }
    }
    float inv = 1.f / l;
    #pragma unroll
    for (int ch = 0; ch < 8; ch++)
        Op[(int64_t)ch * NPOS + pos] = acc[ch] * inv + Lp[(int64_t)ch * NPOS + pos];
}

// ---------------------------------------------------------------------------
// ws layout (floats):
//   buf[16*576*4096]  (cswin tensors; gramP[512*16384] overlaps its start)
//   x1[16*128*4096] | G[16*16384] | AWv[16*32768] | M[16*16384]
// ---------------------------------------------------------------------------
extern "C" void kernel_launch(void* const* d_in, const int* in_sizes, int n_in,
                              void* d_out, int out_size, void* d_ws, size_t ws_size,
                              hipStream_t stream)
{
    (void)in_sizes; (void)n_in; (void)out_size; (void)ws_size;
    const float* x         = (const float*)d_in[0];
    const float* ca_temp   = (const float*)d_in[1];
    const float* ca_qkv_w  = (const float*)d_in[2];
    const float* ca_proj_w = (const float*)d_in[3];
    const float* cs_qk_w   = (const float*)d_in[4];
    const float* cs_v_w    = (const float*)d_in[5];
    const float* cs_vv_w   = (const float*)d_in[6];
    /* d_in[7] = cs_vh_w unused by the reference */
    const float* cs_proj_w = (const float*)d_in[8];
    float* out = (float*)d_out;

    float* buf   = (float*)d_ws;
    float* gramP = buf;                                  // overlaps buf (used first)
    float* x1    = buf + (int64_t)NB * CHB * NPOS;
    float* G     = x1 + (int64_t)NB * 128 * NPOS;
    float* AWv   = G + (int64_t)NB * 16384;
    float* M     = AWv + (int64_t)NB * 32768;

    const int64_t SX = (int64_t)128 * NPOS;
    const int64_t SB2 = (int64_t)CHB * NPOS;
    dim3 blk(256);

    // --- channel attention, collapsed ---
    gram_k<<<dim3(32, NB), blk, 0, stream>>>(x, gramP);
    gram_reduce_k<<<dim3(64, NB), blk, 0, stream>>>(gramP, G);
    ca_small_k<<<dim3(8, NB), blk, 0, stream>>>(G, ca_qkv_w, ca_temp, AWv);
    // M_b = Wp(128x256) @ AWv_b(256x128)   [K=256: Wp has 256 input channels]
    gemm128<<<dim3(1, 2, NB), blk, 0, stream>>>(ca_proj_w, AWv, nullptr, M,
                                                256, 128, 128, 0, 32768, 0, 16384);
    // x1 = x + M_b @ x
    gemm128<<<dim3(32, 2, NB), blk, 0, stream>>>(M, x, x, x1,
                                                 128, NPOS, NPOS, 16384, SX, SX, SX);

    // --- cswin ---
    gemm128<<<dim3(32, 4, NB), blk, 0, stream>>>(cs_qk_w, x1, nullptr, buf,
                                                 128, NPOS, NPOS, 0, SX, 0, SB2);
    gemm128<<<dim3(32, 2, NB), blk, 0, stream>>>(cs_v_w, x1, nullptr, buf + (int64_t)256 * NPOS,
                                                 128, NPOS, NPOS, 0, SX, 0, SB2);
    gemm128<<<dim3(32, 1, NB), blk, 0, stream>>>(cs_vv_w, buf + (int64_t)320 * NPOS, nullptr,
                                                 buf + (int64_t)384 * NPOS,
                                                 64, NPOS, NPOS, 0, SB2, 0, SB2);
    cswin_k<1><<<dim3(16, NB, 8), blk, 0, stream>>>(buf, (int64_t)0,          (int64_t)128 * NPOS,
                                                    (int64_t)256 * NPOS, (int64_t)256 * NPOS,
                                                    (int64_t)448 * NPOS);
    cswin_k<0><<<dim3(16, NB, 8), blk, 0, stream>>>(buf, (int64_t)64 * NPOS,  (int64_t)192 * NPOS,
                                                    (int64_t)320 * NPOS, (int64_t)384 * NPOS,
                                                    (int64_t)512 * NPOS);
    // out = x1 + Wp_cs(128x128) @ concat(out_h, out_v)   [K=128 — was the R12 bug]
    gemm128<<<dim3(32, 2, NB), blk, 0, stream>>>(cs_proj_w, buf + (int64_t)448 * NPOS, x1, out,
                                                 128, NPOS, NPOS, 0, SB2, SX, SX);
}